// Round 20
// baseline (683.795 us; speedup 1.0000x reference)
//
#include <hip/hip_runtime.h>
#include <math.h>

#define SZ    100
#define FILT  51
#define DIM   256
#define MED   512
#define NPOS  80000

#define PERB2 5222400ll          // 2*100*51*512 elems per batch (stacked R/I)
#define PL    2611200ll          // plane stride (100*51*512)
#define HROW  26112              // 51*512

typedef __attribute__((ext_vector_type(8))) short short8v;
typedef __attribute__((ext_vector_type(4))) float f32x4;

__device__ __forceinline__ ushort f2b(float f) {
    union { float f; unsigned u; } x; x.f = f;
    unsigned r = (x.u + 0x7fffu + ((x.u >> 16) & 1u)) >> 16;
    return (ushort)r;
}
__device__ __forceinline__ float b2f(ushort u) {
    union { float f; unsigned u; } x; x.u = ((unsigned)u) << 16;
    return x.f;
}

// direct global->LDS, 16B per lane; dst must be wave-uniform base (lane*16 implied)
__device__ __forceinline__ void gload16(const ushort* g, ushort* l) {
    __builtin_amdgcn_global_load_lds(
        (const __attribute__((address_space(1))) void*)g,
        (__attribute__((address_space(3))) void*)l, 16, 0, 0);
}

#define DPI 3.14159265358979323846

// ================= builders (merged into one launch) =================
__device__ __forceinline__ void dev_A1(int id, ushort* __restrict__ A) {   // [128][128]
    const int rho = id >> 7, w = id & 127;
    float v = 0.f;
    if (w < SZ) {
        if (rho < FILT)          { int m = (rho * w) % SZ;          v =  0.01f * (float)cos(2.0 * DPI * m / SZ); }
        else if (rho < 2 * FILT) { int m = ((rho - FILT) * w) % SZ; v = -0.01f * (float)sin(2.0 * DPI * m / SZ); }
    }
    A[id] = f2b(v);
}

__device__ __forceinline__ void dev_A2(int id, ushort* __restrict__ A, int inv) {  // [256][256]
    const int rho = id >> 8, kk = id & 255;
    float v = 0.f;
    const double sgn = inv ? -1.0 : 1.0;
    if (rho < SZ) {
        if (kk < SZ)           { int m = (rho * kk) % SZ;        v = (float)cos(2.0 * DPI * m / SZ); }
        else if (kk < 2 * SZ)  { int m = (rho * (kk - SZ)) % SZ; v = (float)(sgn * sin(2.0 * DPI * m / SZ)); }
    } else if (rho < 2 * SZ) {
        const int i = rho - SZ;
        if (kk < SZ)           { int m = (i * kk) % SZ;          v = (float)(-sgn * sin(2.0 * DPI * m / SZ)); }
        else if (kk < 2 * SZ)  { int m = (i * (kk - SZ)) % SZ;   v = (float)cos(2.0 * DPI * m / SZ); }
    }
    A[id] = f2b(v);
}

__device__ __forceinline__ void dev_A5(int id, ushort* __restrict__ A) {   // [128][128]
    const int w = id >> 7, kk = id & 127;
    float v = 0.f;
    if (w < SZ) {
        if (kk < FILT) {
            const float wgt = (kk == 0 || kk == FILT - 1) ? 0.01f : 0.02f;
            int m = (w * kk) % SZ; v = wgt * (float)cos(2.0 * DPI * m / SZ);
        } else if (kk < 2 * FILT) {
            const int f = kk - FILT;
            const float wgt = (f == 0 || f == FILT - 1) ? 0.01f : 0.02f;
            int m = (w * f) % SZ; v = -wgt * (float)sin(2.0 * DPI * m / SZ);
        }
    }
    A[id] = f2b(v);
}

// combined block weights, out-major: Wc[n][j(out 0..127)][i(in 0..127)]
__device__ __forceinline__ void dev_wc(int id, const float* __restrict__ wA,
        const float* __restrict__ wB, ushort* __restrict__ Wc) {
    const int n = id >> 14, j = (id >> 7) & 127, i = id & 127;
    float v;
    if (j < 64) v = (i < 64) ? wA[((0 * 8 + n) * 64 + i) * 64 + j]
                             : wA[((1 * 8 + n) * 64 + (i - 64)) * 64 + j];
    else {
        const int jp = j - 64;
        v = (i < 64) ? wB[((1 * 8 + n) * 64 + i) * 64 + jp]
                     : wB[((0 * 8 + n) * 64 + (i - 64)) * 64 + jp];
    }
    Wc[id] = f2b(v);
}

__device__ __forceinline__ void dev_wt(int idx, const float* __restrict__ W,
        ushort* __restrict__ Wt, int K, int N) {
    const int n = idx / K, k = idx % K;
    Wt[idx] = f2b(W[(size_t)k * N + n]);
}

__global__ __launch_bounds__(256) void build_all(
        const float* __restrict__ w1, const float* __restrict__ w11,
        const float* __restrict__ w2, const float* __restrict__ w22,
        const float* __restrict__ pw1_w, const float* __restrict__ pw2_w,
        const float* __restrict__ fc1_w, const float* __restrict__ fc2_w,
        ushort* __restrict__ A1m, ushort* __restrict__ A2m,
        ushort* __restrict__ A4m, ushort* __restrict__ A5m,
        ushort* __restrict__ Wc1, ushort* __restrict__ Wc2,
        ushort* __restrict__ wt1, ushort* __restrict__ wt2,
        ushort* __restrict__ wtf1, ushort* __restrict__ wtf2)
{
    const int b = blockIdx.x;
    const int tid = threadIdx.x;
    if      (b <   64) dev_A1((b          ) * 256 + tid, A1m);
    else if (b <  320) dev_A2((b -    64) * 256 + tid, A2m, 0);
    else if (b <  576) dev_A2((b -   320) * 256 + tid, A4m, 1);
    else if (b <  640) dev_A5((b -   576) * 256 + tid, A5m);
    else if (b < 1152) dev_wc((b -   640) * 256 + tid, w1, w11, Wc1);
    else if (b < 1664) dev_wc((b -  1152) * 256 + tid, w2, w22, Wc2);
    else if (b < 2176) dev_wt((b -  1664) * 256 + tid, pw1_w, wt1, DIM, MED);
    else if (b < 2688) dev_wt((b -  2176) * 256 + tid, pw2_w, wt2, MED, DIM);
    else if (b < 3712) dev_wt((b -  2688) * 256 + tid, fc1_w, wtf1, DIM, 1024);
    else               dev_wt((b -  3712) * 256 + tid, fc2_w, wtf2, 1024, DIM);
}

// ================= fast LayerNorm: one wave per 256-elem row =================
__global__ __launch_bounds__(256) void ln_fast(const float* __restrict__ x,
        const float* __restrict__ g, const float* __restrict__ b, ushort* __restrict__ y)
{
    const int row = blockIdx.x * 4 + (threadIdx.x >> 6);
    const int lane = threadIdx.x & 63;
    const float4 v = *(const float4*)(x + (size_t)row * DIM + lane * 4);
    float s  = v.x + v.y + v.z + v.w;
    float s2 = v.x * v.x + v.y * v.y + v.z * v.z + v.w * v.w;
    #pragma unroll
    for (int off = 32; off > 0; off >>= 1) {
        s  += __shfl_xor(s, off, 64);
        s2 += __shfl_xor(s2, off, 64);
    }
    const float mu  = s * (1.0f / DIM);
    const float var = s2 * (1.0f / DIM) - mu * mu;
    const float rs  = rsqrtf(var + 1e-5f);
    const float4 gv = *(const float4*)(g + lane * 4);
    const float4 bv = *(const float4*)(b + lane * 4);
    ushort4 o;
    o.x = f2b((v.x - mu) * rs * gv.x + bv.x);
    o.y = f2b((v.y - mu) * rs * gv.y + bv.y);
    o.z = f2b((v.z - mu) * rs * gv.z + bv.z);
    o.w = f2b((v.w - mu) * rs * gv.w + bv.w);
    *(ushort4*)(y + (size_t)row * DIM + lane * 4) = o;
}

// ================= dense bf16 MFMA GEMM, global_load_lds + XOR-swizzled LDS =================
// A bf16 [M][K], Bt bf16 [N][K]; EPI: 1 star_relu->fp32, 2 +R->fp32, 3 star_relu->bf16
template<int EPI>
__global__ __launch_bounds__(256) void gemm_mfma(
        const ushort* __restrict__ A16, const ushort* __restrict__ Bt,
        float* __restrict__ Cf, ushort* __restrict__ Cb,
        const float* __restrict__ R, const float* __restrict__ sp, const float* __restrict__ bp,
        int M, int N, int K)
{
    __shared__ ushort As[128][64];   // linear rows (128B); data pre-swizzled at source
    __shared__ ushort Bs[128][64];
    const int t = threadIdx.x;
    const int nwg = gridDim.x;
    const int orig = blockIdx.x;
    const int q = nwg >> 3, rr8 = nwg & 7;
    const int xcd = orig & 7, lo = orig >> 3;
    const int wg = (xcd < rr8 ? xcd * (q + 1) : rr8 * (q + 1) + (xcd - rr8) * q) + lo;
    const int NX = N >> 7;
    const int by = wg / NX, bx = wg % NX;
    const int m0 = by * 128, n0 = bx * 128;

    const int lane = t & 63;
    const int wid = t >> 6;
    const int wr = (wid >> 1) * 64, wc = (wid & 1) * 64;
    const int fr = lane & 15, fg = lane >> 4;
    const int lr = lane >> 3;                          // row-in-segment 0..7
    const int swz = ((lane & 7) ^ lr) * 8;             // inverse-swizzled source col (elems)

    f32x4 acc[4][4];
    #pragma unroll
    for (int i = 0; i < 4; ++i)
        #pragma unroll
        for (int j = 0; j < 4; ++j) acc[i][j] = (f32x4){0.f, 0.f, 0.f, 0.f};

    for (int k0 = 0; k0 < K; k0 += 64) {
        #pragma unroll
        for (int i = 0; i < 4; ++i) {
            const int seg = wid * 4 + i;
            const int row = seg * 8 + lr;
            gload16(A16 + (size_t)(m0 + row) * K + k0 + swz, &As[seg * 8][0]);
            gload16(Bt  + (size_t)(n0 + row) * K + k0 + swz, &Bs[seg * 8][0]);
        }
        __syncthreads();
        #pragma unroll
        for (int ks = 0; ks < 2; ++ks) {
            const int bc = (ks * 64 + fg * 16) ^ ((fr & 7) << 4);   // swizzled byte col
            short8v a[4], b[4];
            #pragma unroll
            for (int mi = 0; mi < 4; ++mi) {
                const int row = wr + mi * 16 + fr;
                a[mi] = *(const short8v*)((const char*)&As[0][0] + row * 128 + bc);
            }
            #pragma unroll
            for (int ni = 0; ni < 4; ++ni) {
                const int row = wc + ni * 16 + fr;
                b[ni] = *(const short8v*)((const char*)&Bs[0][0] + row * 128 + bc);
            }
            #pragma unroll
            for (int mi = 0; mi < 4; ++mi)
                #pragma unroll
                for (int ni = 0; ni < 4; ++ni)
                    acc[mi][ni] = __builtin_amdgcn_mfma_f32_16x16x32_bf16(
                            a[mi], b[ni], acc[mi][ni], 0, 0, 0);
        }
        __syncthreads();
    }
    float s = 0.f, bb = 0.f;
    if (EPI == 1 || EPI == 3) { s = sp[0]; bb = bp[0]; }
    #pragma unroll
    for (int mi = 0; mi < 4; ++mi) {
        #pragma unroll
        for (int r = 0; r < 4; ++r) {
            const int row = m0 + wr + mi * 16 + fg * 4 + r;
            #pragma unroll
            for (int ni = 0; ni < 4; ++ni) {
                const int col = n0 + wc + ni * 16 + fr;
                float v = acc[mi][ni][r];
                const size_t off = (size_t)row * N + col;
                if (EPI == 1) {
                    const float rl = fmaxf(v, 0.f);
                    Cf[off] = s * rl * rl + bb;
                } else if (EPI == 2) {
                    Cf[off] = v + R[off];
                } else {
                    const float rl = fmaxf(v, 0.f);
                    Cb[off] = f2b(s * rl * rl + bb);
                }
            }
        }
    }
}

// ====== fused MLP v8: v7 + lgkm-only mid-chunk barrier (prefetch survives into GEMM2) ======
// 128-row tile, 8 waves. Top barrier = full __syncthreads (vmcnt drain for stage);
// Ms barrier = lgkmcnt(0)-only raw s_barrier so the weight prefetch stays in flight.
__global__ __launch_bounds__(512, 1) void mlp_fused(
        const ushort* __restrict__ y2, const ushort* __restrict__ W1,
        const ushort* __restrict__ W2, float* __restrict__ out,
        const float* __restrict__ sp, const float* __restrict__ bp)
{
    __shared__ ushort W1c[2][64][256];   // 2 x 32 KB, source-swizzled
    __shared__ ushort W2c[2][256][64];   // 2 x 32 KB, source-swizzled
    __shared__ ushort Ms[128][72];       // 18 KB hidden chunk, padded rows
    const int t = threadIdx.x;
    const int lane = t & 63, wid = t >> 6;
    const int grp = wid >> 2;                // row-group 0/1
    const int wid4 = wid & 3;                // col-wave within group
    const int m0 = blockIdx.x * 128;
    const int rb = grp * 64;                 // row-group base (local)
    const int fr = lane & 15, fg = lane >> 4;
    const int wc = wid4 * 64;
    const float s = sp[0], bb = bp[0];

    // ---- y2 tile -> registers ----
    short8v a_y[4][8];
    #pragma unroll
    for (int mi = 0; mi < 4; ++mi)
        #pragma unroll
        for (int ks = 0; ks < 8; ++ks)
            a_y[mi][ks] = *(const short8v*)(y2 + (size_t)(m0 + rb + mi * 16 + fr) * 256 + ks * 32 + fg * 8);

    f32x4 oacc[4][4];
    #pragma unroll
    for (int mi = 0; mi < 4; ++mi)
        #pragma unroll
        for (int ni = 0; ni < 4; ++ni) oacc[mi][ni] = (f32x4){0.f, 0.f, 0.f, 0.f};

    // ---- stage macro: weights for chunk hk into buffer bi (4 gload rounds, 8 waves) ----
#define MLP_STAGE(bi, hkv)                                                            \
    {                                                                                 \
        _Pragma("unroll")                                                             \
        for (int r = 0; r < 4; ++r) {                                                 \
            const int g = r * 8 + wid;                                                \
            {   const int row = g * 2 + (lane >> 5);                                  \
                const int sub = (lane >> 3) & 3;                                      \
                const int src = ((lane & 7) ^ (row & 7)) * 8;                         \
                gload16(W1 + (size_t)((hkv) * 64 + row) * 256 + sub * 64 + src,       \
                        (ushort*)((char*)&W1c[bi][0][0] + g * 1024));                 \
            }                                                                         \
            {   const int row = g * 8 + (lane >> 3);                                  \
                const int src = ((lane & 7) ^ (row & 7)) * 8;                         \
                gload16(W2 + (size_t)row * 1024 + (hkv) * 64 + src,                   \
                        (ushort*)((char*)&W2c[bi][0][0] + g * 1024));                 \
            }                                                                         \
        }                                                                             \
    }

    MLP_STAGE(0, 0);

    for (int hk = 0; hk < 16; ++hk) {
        const int cur = hk & 1;
        __syncthreads();                 // drain stage(hk); prev GEMM2 done before buf^1 overwrite
        if (hk + 1 < 16) MLP_STAGE(cur ^ 1, hk + 1);
        // ---- GEMM1: acc1[mi] = y2tile(group rows) x W1c[cur](h = wid4*16+fr), K=256 ----
        f32x4 acc1[4];
        #pragma unroll
        for (int mi = 0; mi < 4; ++mi) acc1[mi] = (f32x4){0.f, 0.f, 0.f, 0.f};
        const int h = wid4 * 16 + fr;
        #pragma unroll
        for (int ks = 0; ks < 8; ++ks) {
            const int within = (((ks & 1) * 64 + fg * 16) ^ ((h & 7) << 4));
            const short8v b = *(const short8v*)((const char*)&W1c[cur][0][0]
                    + h * 512 + (ks >> 1) * 128 + within);
            #pragma unroll
            for (int mi = 0; mi < 4; ++mi)
                acc1[mi] = __builtin_amdgcn_mfma_f32_16x16x32_bf16(a_y[mi][ks], b, acc1[mi], 0, 0, 0);
        }
        // ---- star_relu -> Ms[rb + row][h] ----
        #pragma unroll
        for (int mi = 0; mi < 4; ++mi)
            #pragma unroll
            for (int rq = 0; rq < 4; ++rq) {
                const int row = rb + mi * 16 + fg * 4 + rq;
                const float rl = fmaxf(acc1[mi][rq], 0.f);
                Ms[row][h] = f2b(s * rl * rl + bb);
            }
        // ---- Ms barrier: LDS-only ordering; weight prefetch (vmcnt) stays in flight ----
        asm volatile("s_waitcnt lgkmcnt(0)" ::: "memory");
        __builtin_amdgcn_s_barrier();
        __builtin_amdgcn_sched_barrier(0);
        // ---- GEMM2: oacc += Ms[group rows][64 h] x W2c[cur](o = wc+ni*16+fr), K=64 ----
        #pragma unroll
        for (int ks2 = 0; ks2 < 2; ++ks2) {
            short8v a[4], b[4];
            #pragma unroll
            for (int mi = 0; mi < 4; ++mi)
                a[mi] = *(const short8v*)((const char*)&Ms[0][0]
                        + (rb + mi * 16 + fr) * 144 + ks2 * 64 + fg * 16);
            #pragma unroll
            for (int ni = 0; ni < 4; ++ni) {
                const int o = wc + ni * 16 + fr;
                b[ni] = *(const short8v*)((const char*)&W2c[cur][0][0]
                        + o * 128 + ((ks2 * 64 + fg * 16) ^ ((o & 7) << 4)));
            }
            #pragma unroll
            for (int mi = 0; mi < 4; ++mi)
                #pragma unroll
                for (int ni = 0; ni < 4; ++ni)
                    oacc[mi][ni] = __builtin_amdgcn_mfma_f32_16x16x32_bf16(
                            a[mi], b[ni], oacc[mi][ni], 0, 0, 0);
        }
    }
#undef MLP_STAGE
    // ---- epilogue: out += oacc ----
    #pragma unroll
    for (int mi = 0; mi < 4; ++mi)
        #pragma unroll
        for (int rq = 0; rq < 4; ++rq) {
            const int row = m0 + rb + mi * 16 + fg * 4 + rq;
            #pragma unroll
            for (int ni = 0; ni < 4; ++ni) {
                const int col = wc + ni * 16 + fr;
                const size_t off = (size_t)row * 256 + col;
                out[off] = oacc[mi][ni][rq] + out[off];
            }
        }
}

// ================= small-A MFMA GEMM for DFT stages (bf16 in/out) =================
// C[rho][n] = sum_k A[rho][k] * B[k][n]; EPI: 0 write, 1 accumulate into C (bf16 RMW)
template<int EPI>
__global__ __launch_bounds__(256) void gemm_dft(
        const ushort* __restrict__ Ag, int Apitch,
        const ushort* __restrict__ Bv, int BzDiv, long BzA, long BzB, int Brs,
        int Bsplit, long BplOff, int Kreal, int Ksteps,
        ushort* __restrict__ Cv, int CzDiv, long CzA, long CzB, int Crs,
        int Csplit, long CplOff, int Climit, int ntiles, int mtiles)
{
    __shared__ ushort As[128][72];
    __shared__ ushort Bs[128][72];
    const int t = threadIdx.x;
    const int per_z = ntiles * mtiles;
    const int z = blockIdx.x / per_z;
    const int rem = blockIdx.x % per_z;
    const int mt = rem % mtiles;
    const int nt = rem / mtiles;
    const int col0 = nt * 128;
    const long Bzbase = (long)(z / BzDiv) * BzA + (long)(z % BzDiv) * BzB;
    const long Czbase = (long)(z / CzDiv) * CzA + (long)(z % CzDiv) * CzB;
    const int lane = t & 63, wid = t >> 6;
    const int wr = (wid >> 1) * 64, wc = (wid & 1) * 64;
    const int fr = lane & 15, fg = lane >> 4;

    f32x4 acc[4][4];
    #pragma unroll
    for (int i = 0; i < 4; ++i)
        #pragma unroll
        for (int j = 0; j < 4; ++j) acc[i][j] = (f32x4){0.f, 0.f, 0.f, 0.f};

    for (int step = 0; step < Ksteps; ++step) {
        const int k0 = step * 64;
        #pragma unroll
        for (int i = 0; i < 4; ++i) {
            const int id = t + 256 * i;
            const int r = id >> 3, j = (id & 7) * 8;
            *(short8v*)&As[r][j] = *(const short8v*)(Ag + (size_t)(mt * 128 + r) * Apitch + k0 + j);
        }
        // stage B slice transposed into Bs[n][k], kblk XOR-swizzled by (n>>3)&7
        #pragma unroll
        for (int i = 0; i < 2; ++i) {
            const int kp = (t >> 4) + 16 * i;     // k-pair 0..31
            const int np = t & 15;                // n-chunk (8 cols)
            const int kg0 = k0 + 2 * kp;
            ushort u0[8] = {0,0,0,0,0,0,0,0}, u1[8] = {0,0,0,0,0,0,0,0};
            if (kg0 < Kreal) {
                const long roff = Bzbase
                        + (kg0 < Bsplit ? (long)kg0 * Brs : BplOff + (long)(kg0 - Bsplit) * Brs)
                        + col0 + np * 8;
                const short8v tv = *(const short8v*)(Bv + roff);
                #pragma unroll
                for (int jj = 0; jj < 8; ++jj) u0[jj] = (ushort)tv[jj];
            }
            if (kg0 + 1 < Kreal) {
                const int kg1 = kg0 + 1;
                const long roff = Bzbase
                        + (kg1 < Bsplit ? (long)kg1 * Brs : BplOff + (long)(kg1 - Bsplit) * Brs)
                        + col0 + np * 8;
                const short8v tv = *(const short8v*)(Bv + roff);
                #pragma unroll
                for (int jj = 0; jj < 8; ++jj) u1[jj] = (ushort)tv[jj];
            }
            const int blk = (kp >> 2) ^ (np & 7);
            #pragma unroll
            for (int jj = 0; jj < 8; ++jj) {
                const int n = np * 8 + jj;
                ushort2 pr; pr.x = u0[jj]; pr.y = u1[jj];
                *(ushort2*)&Bs[n][blk * 8 + ((2 * kp) & 7)] = pr;
            }
        }
        __syncthreads();
        // exact skip: second 32-k slice is all >= Kreal (staged zeros) in K2/K4 tail
        const int nks = (k0 + 32 < Kreal) ? 2 : 1;
        for (int ks = 0; ks < nks; ++ks) {
            const int koff = ks * 32 + fg * 8;
            short8v a[4], b[4];
            #pragma unroll
            for (int mi = 0; mi < 4; ++mi) a[mi] = *(const short8v*)&As[wr + mi * 16 + fr][koff];
            #pragma unroll
            for (int ni = 0; ni < 4; ++ni) {
                const int n = wc + ni * 16 + fr;
                const int blk = (koff >> 3) ^ ((n >> 3) & 7);
                b[ni] = *(const short8v*)&Bs[n][blk * 8];
            }
            #pragma unroll
            for (int mi = 0; mi < 4; ++mi)
                #pragma unroll
                for (int ni = 0; ni < 4; ++ni)
                    acc[mi][ni] = __builtin_amdgcn_mfma_f32_16x16x32_bf16(
                            a[mi], b[ni], acc[mi][ni], 0, 0, 0);
        }
        __syncthreads();
    }
    #pragma unroll
    for (int mi = 0; mi < 4; ++mi) {
        #pragma unroll
        for (int rq = 0; rq < 4; ++rq) {
            const int rho = mt * 128 + wr + mi * 16 + fg * 4 + rq;
            if (rho >= Climit) continue;
            const long rbase = Czbase
                    + (rho < Csplit ? (long)rho * Crs : CplOff + (long)(rho - Csplit) * Crs);
            #pragma unroll
            for (int ni = 0; ni < 4; ++ni) {
                const long caddr = rbase + col0 + wc + ni * 16 + fr;
                float v = acc[mi][ni][rq];
                if (EPI == 1) v += b2f(Cv[caddr]);
                Cv[caddr] = f2b(v);
            }
        }
    }
}

// ======== fused block-diagonal complex 2-layer MLP: both layers in one kernel ========
__global__ __launch_bounds__(256) void bmm_fused(
        ushort* __restrict__ F2,
        const ushort* __restrict__ Wc1, const ushort* __restrict__ Wc2,
        const float* __restrict__ bias1, const float* __restrict__ bias2,
        const float* __restrict__ sRp, const float* __restrict__ bRp,
        const float* __restrict__ sIp, const float* __restrict__ bIp)
{
    const int MT = 40;
    const int wg = blockIdx.x;
    const int mt = wg % MT;
    const int n  = (wg / MT) & 7;
    const int bl = wg / (MT * 8);
    const long FB = (long)bl * PERB2;
    const int r0 = mt * 128;
    __shared__ ushort As[128][64];    // phase A: F2 rows; phase B: Wc2 k 0..63
    __shared__ ushort Ws[128][64];    // phase A: Wc1 slice; phase B: Wc2 k 64..127
    __shared__ ushort Ms[128][136];   // o1 tile bf16, padded rows (272B)
    const int t = threadIdx.x;
    const int lane = t & 63, wid = t >> 6;
    const int wr = (wid >> 1) * 64, wc = (wid & 1) * 64;
    const int fr = lane & 15, fg = lane >> 4;
    const int lr = lane >> 3;
    const int swz = ((lane & 7) ^ lr) * 8;

    f32x4 acc[4][4];
    #pragma unroll
    for (int i = 0; i < 4; ++i)
        #pragma unroll
        for (int j = 0; j < 4; ++j) acc[i][j] = (f32x4){0.f, 0.f, 0.f, 0.f};

    // ---- phase A (identical to verified gemm_bmm<0> loop) ----
    for (int step = 0; step < 2; ++step) {
        #pragma unroll
        for (int i = 0; i < 4; ++i) {
            const int seg = wid * 4 + i;
            const int row = seg * 8 + lr;
            const long r = r0 + row;
            gload16(F2 + FB + (step ? PL : 0) + r * 512 + n * 64 + swz, &As[seg * 8][0]);
            gload16(Wc1 + ((long)n << 14) + (long)row * 128 + step * 64 + swz, &Ws[seg * 8][0]);
        }
        __syncthreads();
        #pragma unroll
        for (int ks = 0; ks < 2; ++ks) {
            const int bc = (ks * 64 + fg * 16) ^ ((fr & 7) << 4);
            short8v a[4], b[4];
            #pragma unroll
            for (int mi = 0; mi < 4; ++mi) {
                const int row = wr + mi * 16 + fr;
                a[mi] = *(const short8v*)((const char*)&As[0][0] + row * 128 + bc);
            }
            #pragma unroll
            for (int ni = 0; ni < 4; ++ni) {
                const int row = wc + ni * 16 + fr;
                b[ni] = *(const short8v*)((const char*)&Ws[0][0] + row * 128 + bc);
            }
            #pragma unroll
            for (int mi = 0; mi < 4; ++mi)
                #pragma unroll
                for (int ni = 0; ni < 4; ++ni)
                    acc[mi][ni] = __builtin_amdgcn_mfma_f32_16x16x32_bf16(
                            a[mi], b[ni], acc[mi][ni], 0, 0, 0);
        }
        __syncthreads();
    }
    // ---- transition: Ms = star_relu(o1); stage full Wc2 into As (k<64) + Ws (k>=64) ----
    #pragma unroll
    for (int r4 = 0; r4 < 4; ++r4) {
        const int g = r4 * 4 + wid;
        const int row = g * 8 + (lane >> 3);
        const int src = ((lane & 7) ^ (row & 7)) * 8;
        gload16(Wc2 + ((long)n << 14) + (long)row * 128 + src,
                (ushort*)((char*)&As[0][0] + g * 1024));
        gload16(Wc2 + ((long)n << 14) + (long)row * 128 + 64 + src,
                (ushort*)((char*)&Ws[0][0] + g * 1024));
    }
    {
        const float sR = sRp[0], bR = bRp[0], sI = sIp[0], bI = bIp[0];
        #pragma unroll
        for (int mi = 0; mi < 4; ++mi)
            #pragma unroll
            for (int rq = 0; rq < 4; ++rq) {
                const int row = wr + mi * 16 + fg * 4 + rq;
                #pragma unroll
                for (int ni = 0; ni < 4; ++ni) {
                    const int j = wc + ni * 16 + fr;
                    const float u = acc[mi][ni][rq] + bias1[(j < 64 ? 0 : 512) + n * 64 + (j & 63)];
                    const float s  = (j < 64) ? sR : sI;
                    const float bb = (j < 64) ? bR : bI;
                    const float rl = fmaxf(u, 0.f);
                    Ms[row][j] = f2b(s * rl * rl + bb);
                }
            }
    }
    __syncthreads();        // Ms visible + Wc2 gloads drained (phase B reads them)
    // ---- phase B: barrier-free (Ms + As/Ws read-only) ----
    #pragma unroll
    for (int i = 0; i < 4; ++i)
        #pragma unroll
        for (int j = 0; j < 4; ++j) acc[i][j] = (f32x4){0.f, 0.f, 0.f, 0.f};
    #pragma unroll
    for (int step = 0; step < 2; ++step) {
        const char* basep = step ? (const char*)&Ws[0][0] : (const char*)&As[0][0];
        #pragma unroll
        for (int ks = 0; ks < 2; ++ks) {
            const int bc = (ks * 64 + fg * 16) ^ ((fr & 7) << 4);
            short8v a[4], b[4];
            #pragma unroll
            for (int mi = 0; mi < 4; ++mi) {
                const int row = wr + mi * 16 + fr;
                a[mi] = *(const short8v*)((const char*)&Ms[0][0]
                        + row * 272 + step * 128 + ks * 64 + fg * 16);
            }
            #pragma unroll
            for (int ni = 0; ni < 4; ++ni) {
                const int row = wc + ni * 16 + fr;
                b[ni] = *(const short8v*)(basep + row * 128 + bc);
            }
            #pragma unroll
            for (int mi = 0; mi < 4; ++mi)
                #pragma unroll
                for (int ni = 0; ni < 4; ++ni)
                    acc[mi][ni] = __builtin_amdgcn_mfma_f32_16x16x32_bf16(
                            a[mi], b[ni], acc[mi][ni], 0, 0, 0);
        }
    }
    // ---- epilogue: F2 = (o2 + b2) * F2 ----
    #pragma unroll
    for (int mi = 0; mi < 4; ++mi) {
        #pragma unroll
        for (int rq = 0; rq < 4; ++rq) {
            const int r = r0 + wr + mi * 16 + fg * 4 + rq;
            if (r >= 5100) continue;
            #pragma unroll
            for (int ni = 0; ni < 4; ++ni) {
                const int j = wc + ni * 16 + fr;
                const float u = acc[mi][ni][rq] + bias2[(j < 64 ? 0 : 512) + n * 64 + (j & 63)];
                const long ma = FB + (j < 64 ? 0 : PL) + (long)r * 512 + n * 64 + (j & 63);
                F2[ma] = f2b(u * b2f(F2[ma]));
            }
        }
    }
}

// ================= launcher =================
extern "C" void kernel_launch(void* const* d_in, const int* in_sizes, int n_in,
                              void* d_out, int out_size, void* d_ws, size_t ws_size,
                              hipStream_t stream) {
    (void)in_sizes; (void)n_in; (void)out_size;
    const float* x        = (const float*)d_in[0];
    const float* ln1_g    = (const float*)d_in[1];
    const float* ln1_b    = (const float*)d_in[2];
    const float* pw1_w    = (const float*)d_in[3];
    const float* act1_s   = (const float*)d_in[4];
    const float* act1_b   = (const float*)d_in[5];
    const float* w1       = (const float*)d_in[6];
    const float* w11      = (const float*)d_in[7];
    const float* b1       = (const float*)d_in[8];
    const float* w2       = (const float*)d_in[9];
    const float* w22      = (const float*)d_in[10];
    const float* b2       = (const float*)d_in[11];
    const float* actr_s   = (const float*)d_in[12];
    const float* actr_b   = (const float*)d_in[13];
    const float* acti_s   = (const float*)d_in[14];
    const float* acti_b   = (const float*)d_in[15];
    const float* pw2_w    = (const float*)d_in[16];
    const float* ln2_g    = (const float*)d_in[17];
    const float* ln2_b    = (const float*)d_in[18];
    const float* fc1_w    = (const float*)d_in[19];
    const float* mlp_s    = (const float*)d_in[20];
    const float* mlp_b    = (const float*)d_in[21];
    const float* fc2_w    = (const float*)d_in[22];
    float* out = (float*)d_out;
    float* ws  = (float*)d_ws;

    const size_t HBUF_F = 40960000ull;          // h16 region (bf16 uses half)
    const size_t MATS_F = 610000ull;
    const size_t ws_floats = ws_size / 4;
    int CB = 4;                                 // L3 sweet spot: all freq buffers resident
    while (CB > 1 && HBUF_F + (size_t)CB * (size_t)PERB2 + MATS_F > ws_floats) CB >>= 1;

    float* hbuf = ws;
    ushort* h16 = (ushort*)hbuf;                 // [80000][512] bf16
    ushort* tA16 = (ushort*)(ws + HBUF_F);       // CB*PERB2 ushorts
    ushort* tB16 = tA16 + (size_t)CB * PERB2;
    ushort* mats = tB16 + (size_t)CB * PERB2;
    ushort* A1m  = mats;
    ushort* A2m  = A1m + 16384;
    ushort* A4m  = A2m + 65536;
    ushort* A5m  = A4m + 65536;
    ushort* Wc1  = A5m + 16384;
    ushort* Wc2  = Wc1 + 131072;
    ushort* wt1  = Wc2 + 131072;
    ushort* wt2  = wt1 + 131072;
    ushort* wtf1 = wt2 + 131072;
    ushort* wtf2 = wtf1 + 262144;

    ushort* y16 = (ushort*)out;                          // LN1 out (scratch until pw2)
    ushort* y2  = (ushort*)hbuf;                         // LN2 out (h16 dead after pw2)

    build_all<<<4736, 256, 0, stream>>>(w1, w11, w2, w22, pw1_w, pw2_w, fc1_w, fc2_w,
            A1m, A2m, A4m, A5m, Wc1, Wc2, wt1, wt2, wtf1, wtf2);

    // ---- token mixer ----
    ln_fast<<<NPOS / 4, 256, 0, stream>>>(x, ln1_g, ln1_b, y16);
    gemm_mfma<3><<<(NPOS / 128) * (MED / 128), 256, 0, stream>>>(
            y16, wt1, nullptr, h16, nullptr, act1_s, act1_b, NPOS, MED, DIM);

    for (int b0 = 0; b0 < 8; b0 += CB) {
        ushort* hchunk = h16 + (size_t)b0 * (SZ * SZ * MED);
        // K1: rfft along W -> tA
        gemm_dft<0><<<CB * 100 * 4, 256, 0, stream>>>(
                A1m, 128, hchunk, 1, 51200, 0, 512, 100, 0, 100, 2,
                tA16, 100, PERB2, HROW, 512, 51, PL, 102, 4, 1);
        // K2: forward DFT along H: tA -> tB
        gemm_dft<0><<<CB * 408, 256, 0, stream>>>(
                A2m, 256, tA16, 1, PERB2, 0, HROW, 100, PL, 200, 4,
                tB16, 1, PERB2, 0, HROW, 100, PL, 200, 204, 2);
        // fused bmm: both complex-MLP layers, F2 updated in place (no G1 round-trip)
        bmm_fused<<<CB * 320, 256, 0, stream>>>(
                tB16, Wc1, Wc2, b1, b2, actr_s, actr_b, acti_s, acti_b);
        // K4: inverse DFT along H: tB -> tA
        gemm_dft<0><<<CB * 408, 256, 0, stream>>>(
                A4m, 256, tB16, 1, PERB2, 0, HROW, 100, PL, 200, 4,
                tA16, 1, PERB2, 0, HROW, 100, PL, 200, 204, 2);
        // K5: irfft along W + skip accumulate into bf16 h
        gemm_dft<1><<<CB * 100 * 4, 256, 0, stream>>>(
                A5m, 128, tA16, 100, PERB2, HROW, 512, 51, PL, 102, 2,
                hchunk, 1, 51200, 0, 512, 100, 0, 100, 4, 1);
    }

    gemm_mfma<2><<<(NPOS / 128) * (DIM / 128), 256, 0, stream>>>(
            h16, wt2, out, nullptr, x, nullptr, nullptr, NPOS, DIM, MED);

    // ---- MLP branch: LN2 + fused MLP v8 (lgkm-only mid barrier) ----
    ln_fast<<<NPOS / 4, 256, 0, stream>>>(out, ln2_g, ln2_b, y2);
    mlp_fused<<<NPOS / 128, 512, 0, stream>>>(y2, wtf1, wtf2, out, mlp_s, mlp_b);
}

// Round 21
// 678.881 us; speedup vs baseline: 1.0072x; 1.0072x over previous
//
#include <hip/hip_runtime.h>
#include <math.h>

#define SZ    100
#define FILT  51
#define DIM   256
#define MED   512
#define NPOS  80000

#define PERB2 5222400ll          // 2*100*51*512 elems per batch (stacked R/I)
#define PL    2611200ll          // plane stride (100*51*512)
#define HROW  26112              // 51*512

typedef __attribute__((ext_vector_type(8))) short short8v;
typedef __attribute__((ext_vector_type(4))) float f32x4;

__device__ __forceinline__ ushort f2b(float f) {
    union { float f; unsigned u; } x; x.f = f;
    unsigned r = (x.u + 0x7fffu + ((x.u >> 16) & 1u)) >> 16;
    return (ushort)r;
}
__device__ __forceinline__ float b2f(ushort u) {
    union { float f; unsigned u; } x; x.u = ((unsigned)u) << 16;
    return x.f;
}

// direct global->LDS, 16B per lane; dst must be wave-uniform base (lane*16 implied)
__device__ __forceinline__ void gload16(const ushort* g, ushort* l) {
    __builtin_amdgcn_global_load_lds(
        (const __attribute__((address_space(1))) void*)g,
        (__attribute__((address_space(3))) void*)l, 16, 0, 0);
}

#define DPI 3.14159265358979323846

// ================= builders (merged into one launch) =================
__device__ __forceinline__ void dev_A1(int id, ushort* __restrict__ A) {   // [128][128]
    const int rho = id >> 7, w = id & 127;
    float v = 0.f;
    if (w < SZ) {
        if (rho < FILT)          { int m = (rho * w) % SZ;          v =  0.01f * (float)cos(2.0 * DPI * m / SZ); }
        else if (rho < 2 * FILT) { int m = ((rho - FILT) * w) % SZ; v = -0.01f * (float)sin(2.0 * DPI * m / SZ); }
    }
    A[id] = f2b(v);
}

__device__ __forceinline__ void dev_A2(int id, ushort* __restrict__ A, int inv) {  // [256][256]
    const int rho = id >> 8, kk = id & 255;
    float v = 0.f;
    const double sgn = inv ? -1.0 : 1.0;
    if (rho < SZ) {
        if (kk < SZ)           { int m = (rho * kk) % SZ;        v = (float)cos(2.0 * DPI * m / SZ); }
        else if (kk < 2 * SZ)  { int m = (rho * (kk - SZ)) % SZ; v = (float)(sgn * sin(2.0 * DPI * m / SZ)); }
    } else if (rho < 2 * SZ) {
        const int i = rho - SZ;
        if (kk < SZ)           { int m = (i * kk) % SZ;          v = (float)(-sgn * sin(2.0 * DPI * m / SZ)); }
        else if (kk < 2 * SZ)  { int m = (i * (kk - SZ)) % SZ;   v = (float)cos(2.0 * DPI * m / SZ); }
    }
    A[id] = f2b(v);
}

__device__ __forceinline__ void dev_A5(int id, ushort* __restrict__ A) {   // [128][128]
    const int w = id >> 7, kk = id & 127;
    float v = 0.f;
    if (w < SZ) {
        if (kk < FILT) {
            const float wgt = (kk == 0 || kk == FILT - 1) ? 0.01f : 0.02f;
            int m = (w * kk) % SZ; v = wgt * (float)cos(2.0 * DPI * m / SZ);
        } else if (kk < 2 * FILT) {
            const int f = kk - FILT;
            const float wgt = (f == 0 || f == FILT - 1) ? 0.01f : 0.02f;
            int m = (w * f) % SZ; v = -wgt * (float)sin(2.0 * DPI * m / SZ);
        }
    }
    A[id] = f2b(v);
}

// combined block weights, out-major: Wc[n][j(out 0..127)][i(in 0..127)]
__device__ __forceinline__ void dev_wc(int id, const float* __restrict__ wA,
        const float* __restrict__ wB, ushort* __restrict__ Wc) {
    const int n = id >> 14, j = (id >> 7) & 127, i = id & 127;
    float v;
    if (j < 64) v = (i < 64) ? wA[((0 * 8 + n) * 64 + i) * 64 + j]
                             : wA[((1 * 8 + n) * 64 + (i - 64)) * 64 + j];
    else {
        const int jp = j - 64;
        v = (i < 64) ? wB[((1 * 8 + n) * 64 + i) * 64 + jp]
                     : wB[((0 * 8 + n) * 64 + (i - 64)) * 64 + jp];
    }
    Wc[id] = f2b(v);
}

__device__ __forceinline__ void dev_wt(int idx, const float* __restrict__ W,
        ushort* __restrict__ Wt, int K, int N) {
    const int n = idx / K, k = idx % K;
    Wt[idx] = f2b(W[(size_t)k * N + n]);
}

__global__ __launch_bounds__(256) void build_all(
        const float* __restrict__ w1, const float* __restrict__ w11,
        const float* __restrict__ w2, const float* __restrict__ w22,
        const float* __restrict__ pw1_w, const float* __restrict__ pw2_w,
        const float* __restrict__ fc1_w, const float* __restrict__ fc2_w,
        ushort* __restrict__ A1m, ushort* __restrict__ A2m,
        ushort* __restrict__ A4m, ushort* __restrict__ A5m,
        ushort* __restrict__ Wc1, ushort* __restrict__ Wc2,
        ushort* __restrict__ wt1, ushort* __restrict__ wt2,
        ushort* __restrict__ wtf1, ushort* __restrict__ wtf2)
{
    const int b = blockIdx.x;
    const int tid = threadIdx.x;
    if      (b <   64) dev_A1((b          ) * 256 + tid, A1m);
    else if (b <  320) dev_A2((b -    64) * 256 + tid, A2m, 0);
    else if (b <  576) dev_A2((b -   320) * 256 + tid, A4m, 1);
    else if (b <  640) dev_A5((b -   576) * 256 + tid, A5m);
    else if (b < 1152) dev_wc((b -   640) * 256 + tid, w1, w11, Wc1);
    else if (b < 1664) dev_wc((b -  1152) * 256 + tid, w2, w22, Wc2);
    else if (b < 2176) dev_wt((b -  1664) * 256 + tid, pw1_w, wt1, DIM, MED);
    else if (b < 2688) dev_wt((b -  2176) * 256 + tid, pw2_w, wt2, MED, DIM);
    else if (b < 3712) dev_wt((b -  2688) * 256 + tid, fc1_w, wtf1, DIM, 1024);
    else               dev_wt((b -  3712) * 256 + tid, fc2_w, wtf2, 1024, DIM);
}

// ================= fast LayerNorm: one wave per 256-elem row =================
__global__ __launch_bounds__(256) void ln_fast(const float* __restrict__ x,
        const float* __restrict__ g, const float* __restrict__ b, ushort* __restrict__ y)
{
    const int row = blockIdx.x * 4 + (threadIdx.x >> 6);
    const int lane = threadIdx.x & 63;
    const float4 v = *(const float4*)(x + (size_t)row * DIM + lane * 4);
    float s  = v.x + v.y + v.z + v.w;
    float s2 = v.x * v.x + v.y * v.y + v.z * v.z + v.w * v.w;
    #pragma unroll
    for (int off = 32; off > 0; off >>= 1) {
        s  += __shfl_xor(s, off, 64);
        s2 += __shfl_xor(s2, off, 64);
    }
    const float mu  = s * (1.0f / DIM);
    const float var = s2 * (1.0f / DIM) - mu * mu;
    const float rs  = rsqrtf(var + 1e-5f);
    const float4 gv = *(const float4*)(g + lane * 4);
    const float4 bv = *(const float4*)(b + lane * 4);
    ushort4 o;
    o.x = f2b((v.x - mu) * rs * gv.x + bv.x);
    o.y = f2b((v.y - mu) * rs * gv.y + bv.y);
    o.z = f2b((v.z - mu) * rs * gv.z + bv.z);
    o.w = f2b((v.w - mu) * rs * gv.w + bv.w);
    *(ushort4*)(y + (size_t)row * DIM + lane * 4) = o;
}

// ================= dense bf16 MFMA GEMM, global_load_lds + XOR-swizzled LDS =================
// A bf16 [M][K], Bt bf16 [N][K]; EPI: 1 star_relu->fp32, 2 +R->fp32, 3 star_relu->bf16
template<int EPI>
__global__ __launch_bounds__(256) void gemm_mfma(
        const ushort* __restrict__ A16, const ushort* __restrict__ Bt,
        float* __restrict__ Cf, ushort* __restrict__ Cb,
        const float* __restrict__ R, const float* __restrict__ sp, const float* __restrict__ bp,
        int M, int N, int K)
{
    __shared__ ushort As[128][64];   // linear rows (128B); data pre-swizzled at source
    __shared__ ushort Bs[128][64];
    const int t = threadIdx.x;
    const int nwg = gridDim.x;
    const int orig = blockIdx.x;
    const int q = nwg >> 3, rr8 = nwg & 7;
    const int xcd = orig & 7, lo = orig >> 3;
    const int wg = (xcd < rr8 ? xcd * (q + 1) : rr8 * (q + 1) + (xcd - rr8) * q) + lo;
    const int NX = N >> 7;
    const int by = wg / NX, bx = wg % NX;
    const int m0 = by * 128, n0 = bx * 128;

    const int lane = t & 63;
    const int wid = t >> 6;
    const int wr = (wid >> 1) * 64, wc = (wid & 1) * 64;
    const int fr = lane & 15, fg = lane >> 4;
    const int lr = lane >> 3;                          // row-in-segment 0..7
    const int swz = ((lane & 7) ^ lr) * 8;             // inverse-swizzled source col (elems)

    f32x4 acc[4][4];
    #pragma unroll
    for (int i = 0; i < 4; ++i)
        #pragma unroll
        for (int j = 0; j < 4; ++j) acc[i][j] = (f32x4){0.f, 0.f, 0.f, 0.f};

    for (int k0 = 0; k0 < K; k0 += 64) {
        #pragma unroll
        for (int i = 0; i < 4; ++i) {
            const int seg = wid * 4 + i;
            const int row = seg * 8 + lr;
            gload16(A16 + (size_t)(m0 + row) * K + k0 + swz, &As[seg * 8][0]);
            gload16(Bt  + (size_t)(n0 + row) * K + k0 + swz, &Bs[seg * 8][0]);
        }
        __syncthreads();
        #pragma unroll
        for (int ks = 0; ks < 2; ++ks) {
            const int bc = (ks * 64 + fg * 16) ^ ((fr & 7) << 4);   // swizzled byte col
            short8v a[4], b[4];
            #pragma unroll
            for (int mi = 0; mi < 4; ++mi) {
                const int row = wr + mi * 16 + fr;
                a[mi] = *(const short8v*)((const char*)&As[0][0] + row * 128 + bc);
            }
            #pragma unroll
            for (int ni = 0; ni < 4; ++ni) {
                const int row = wc + ni * 16 + fr;
                b[ni] = *(const short8v*)((const char*)&Bs[0][0] + row * 128 + bc);
            }
            #pragma unroll
            for (int mi = 0; mi < 4; ++mi)
                #pragma unroll
                for (int ni = 0; ni < 4; ++ni)
                    acc[mi][ni] = __builtin_amdgcn_mfma_f32_16x16x32_bf16(
                            a[mi], b[ni], acc[mi][ni], 0, 0, 0);
        }
        __syncthreads();
    }
    float s = 0.f, bb = 0.f;
    if (EPI == 1 || EPI == 3) { s = sp[0]; bb = bp[0]; }
    #pragma unroll
    for (int mi = 0; mi < 4; ++mi) {
        #pragma unroll
        for (int r = 0; r < 4; ++r) {
            const int row = m0 + wr + mi * 16 + fg * 4 + r;
            #pragma unroll
            for (int ni = 0; ni < 4; ++ni) {
                const int col = n0 + wc + ni * 16 + fr;
                float v = acc[mi][ni][r];
                const size_t off = (size_t)row * N + col;
                if (EPI == 1) {
                    const float rl = fmaxf(v, 0.f);
                    Cf[off] = s * rl * rl + bb;
                } else if (EPI == 2) {
                    Cf[off] = v + R[off];
                } else {
                    const float rl = fmaxf(v, 0.f);
                    Cb[off] = f2b(s * rl * rl + bb);
                }
            }
        }
    }
}

// ====== fused MLP v7 (benched best, 163.7 us): double-buffered weight staging ======
// 128-row tile, 8 waves (2 row-groups x 4 col-waves). 2 barriers per hk chunk.
// LDS: 2x(W1c+W2c) = 128 KB + Ms 18.4 KB = 146.4 KB -> 1 block/CU.
__global__ __launch_bounds__(512, 1) void mlp_fused(
        const ushort* __restrict__ y2, const ushort* __restrict__ W1,
        const ushort* __restrict__ W2, float* __restrict__ out,
        const float* __restrict__ sp, const float* __restrict__ bp)
{
    __shared__ ushort W1c[2][64][256];   // 2 x 32 KB, source-swizzled
    __shared__ ushort W2c[2][256][64];   // 2 x 32 KB, source-swizzled
    __shared__ ushort Ms[128][72];       // 18 KB hidden chunk, padded rows
    const int t = threadIdx.x;
    const int lane = t & 63, wid = t >> 6;
    const int grp = wid >> 2;                // row-group 0/1
    const int wid4 = wid & 3;                // col-wave within group
    const int m0 = blockIdx.x * 128;
    const int rb = grp * 64;                 // row-group base (local)
    const int fr = lane & 15, fg = lane >> 4;
    const int wc = wid4 * 64;
    const float s = sp[0], bb = bp[0];

    // ---- y2 tile -> registers ----
    short8v a_y[4][8];
    #pragma unroll
    for (int mi = 0; mi < 4; ++mi)
        #pragma unroll
        for (int ks = 0; ks < 8; ++ks)
            a_y[mi][ks] = *(const short8v*)(y2 + (size_t)(m0 + rb + mi * 16 + fr) * 256 + ks * 32 + fg * 8);

    f32x4 oacc[4][4];
    #pragma unroll
    for (int mi = 0; mi < 4; ++mi)
        #pragma unroll
        for (int ni = 0; ni < 4; ++ni) oacc[mi][ni] = (f32x4){0.f, 0.f, 0.f, 0.f};

    // ---- stage macro: weights for chunk hk into buffer bi (4 gload rounds, 8 waves) ----
#define MLP_STAGE(bi, hkv)                                                            \
    {                                                                                 \
        _Pragma("unroll")                                                             \
        for (int r = 0; r < 4; ++r) {                                                 \
            const int g = r * 8 + wid;                                                \
            {   const int row = g * 2 + (lane >> 5);                                  \
                const int sub = (lane >> 3) & 3;                                      \
                const int src = ((lane & 7) ^ (row & 7)) * 8;                         \
                gload16(W1 + (size_t)((hkv) * 64 + row) * 256 + sub * 64 + src,       \
                        (ushort*)((char*)&W1c[bi][0][0] + g * 1024));                 \
            }                                                                         \
            {   const int row = g * 8 + (lane >> 3);                                  \
                const int src = ((lane & 7) ^ (row & 7)) * 8;                         \
                gload16(W2 + (size_t)row * 1024 + (hkv) * 64 + src,                   \
                        (ushort*)((char*)&W2c[bi][0][0] + g * 1024));                 \
            }                                                                         \
        }                                                                             \
    }

    MLP_STAGE(0, 0);

    for (int hk = 0; hk < 16; ++hk) {
        const int cur = hk & 1;
        __syncthreads();                 // drain stage(hk); prev GEMM2 done before buf^1 overwrite
        if (hk + 1 < 16) MLP_STAGE(cur ^ 1, hk + 1);
        // ---- GEMM1: acc1[mi] = y2tile(group rows) x W1c[cur](h = wid4*16+fr), K=256 ----
        f32x4 acc1[4];
        #pragma unroll
        for (int mi = 0; mi < 4; ++mi) acc1[mi] = (f32x4){0.f, 0.f, 0.f, 0.f};
        const int h = wid4 * 16 + fr;
        #pragma unroll
        for (int ks = 0; ks < 8; ++ks) {
            const int within = (((ks & 1) * 64 + fg * 16) ^ ((h & 7) << 4));
            const short8v b = *(const short8v*)((const char*)&W1c[cur][0][0]
                    + h * 512 + (ks >> 1) * 128 + within);
            #pragma unroll
            for (int mi = 0; mi < 4; ++mi)
                acc1[mi] = __builtin_amdgcn_mfma_f32_16x16x32_bf16(a_y[mi][ks], b, acc1[mi], 0, 0, 0);
        }
        // ---- star_relu -> Ms[rb + row][h] ----
        #pragma unroll
        for (int mi = 0; mi < 4; ++mi)
            #pragma unroll
            for (int rq = 0; rq < 4; ++rq) {
                const int row = rb + mi * 16 + fg * 4 + rq;
                const float rl = fmaxf(acc1[mi][rq], 0.f);
                Ms[row][h] = f2b(s * rl * rl + bb);
            }
        __syncthreads();                 // Ms visible
        // ---- GEMM2: oacc += Ms[group rows][64 h] x W2c[cur](o = wc+ni*16+fr), K=64 ----
        #pragma unroll
        for (int ks2 = 0; ks2 < 2; ++ks2) {
            short8v a[4], b[4];
            #pragma unroll
            for (int mi = 0; mi < 4; ++mi)
                a[mi] = *(const short8v*)((const char*)&Ms[0][0]
                        + (rb + mi * 16 + fr) * 144 + ks2 * 64 + fg * 16);
            #pragma unroll
            for (int ni = 0; ni < 4; ++ni) {
                const int o = wc + ni * 16 + fr;
                b[ni] = *(const short8v*)((const char*)&W2c[cur][0][0]
                        + o * 128 + ((ks2 * 64 + fg * 16) ^ ((o & 7) << 4)));
            }
            #pragma unroll
            for (int mi = 0; mi < 4; ++mi)
                #pragma unroll
                for (int ni = 0; ni < 4; ++ni)
                    oacc[mi][ni] = __builtin_amdgcn_mfma_f32_16x16x32_bf16(
                            a[mi], b[ni], oacc[mi][ni], 0, 0, 0);
        }
    }
#undef MLP_STAGE
    // ---- epilogue: out += oacc ----
    #pragma unroll
    for (int mi = 0; mi < 4; ++mi)
        #pragma unroll
        for (int rq = 0; rq < 4; ++rq) {
            const int row = m0 + rb + mi * 16 + fg * 4 + rq;
            #pragma unroll
            for (int ni = 0; ni < 4; ++ni) {
                const int col = wc + ni * 16 + fr;
                const size_t off = (size_t)row * 256 + col;
                out[off] = oacc[mi][ni][rq] + out[off];
            }
        }
}

// ================= small-A MFMA GEMM for DFT stages (bf16 in/out) =================
// C[rho][n] = sum_k A[rho][k] * B[k][n]; EPI: 0 write, 1 accumulate into C (bf16 RMW)
template<int EPI>
__global__ __launch_bounds__(256) void gemm_dft(
        const ushort* __restrict__ Ag, int Apitch,
        const ushort* __restrict__ Bv, int BzDiv, long BzA, long BzB, int Brs,
        int Bsplit, long BplOff, int Kreal, int Ksteps,
        ushort* __restrict__ Cv, int CzDiv, long CzA, long CzB, int Crs,
        int Csplit, long CplOff, int Climit, int ntiles, int mtiles)
{
    __shared__ ushort As[128][72];
    __shared__ ushort Bs[128][72];
    const int t = threadIdx.x;
    const int per_z = ntiles * mtiles;
    const int z = blockIdx.x / per_z;
    const int rem = blockIdx.x % per_z;
    const int mt = rem % mtiles;
    const int nt = rem / mtiles;
    const int col0 = nt * 128;
    const long Bzbase = (long)(z / BzDiv) * BzA + (long)(z % BzDiv) * BzB;
    const long Czbase = (long)(z / CzDiv) * CzA + (long)(z % CzDiv) * CzB;
    const int lane = t & 63, wid = t >> 6;
    const int wr = (wid >> 1) * 64, wc = (wid & 1) * 64;
    const int fr = lane & 15, fg = lane >> 4;

    f32x4 acc[4][4];
    #pragma unroll
    for (int i = 0; i < 4; ++i)
        #pragma unroll
        for (int j = 0; j < 4; ++j) acc[i][j] = (f32x4){0.f, 0.f, 0.f, 0.f};

    for (int step = 0; step < Ksteps; ++step) {
        const int k0 = step * 64;
        #pragma unroll
        for (int i = 0; i < 4; ++i) {
            const int id = t + 256 * i;
            const int r = id >> 3, j = (id & 7) * 8;
            *(short8v*)&As[r][j] = *(const short8v*)(Ag + (size_t)(mt * 128 + r) * Apitch + k0 + j);
        }
        // stage B slice transposed into Bs[n][k], kblk XOR-swizzled by (n>>3)&7
        #pragma unroll
        for (int i = 0; i < 2; ++i) {
            const int kp = (t >> 4) + 16 * i;     // k-pair 0..31
            const int np = t & 15;                // n-chunk (8 cols)
            const int kg0 = k0 + 2 * kp;
            ushort u0[8] = {0,0,0,0,0,0,0,0}, u1[8] = {0,0,0,0,0,0,0,0};
            if (kg0 < Kreal) {
                const long roff = Bzbase
                        + (kg0 < Bsplit ? (long)kg0 * Brs : BplOff + (long)(kg0 - Bsplit) * Brs)
                        + col0 + np * 8;
                const short8v tv = *(const short8v*)(Bv + roff);
                #pragma unroll
                for (int jj = 0; jj < 8; ++jj) u0[jj] = (ushort)tv[jj];
            }
            if (kg0 + 1 < Kreal) {
                const int kg1 = kg0 + 1;
                const long roff = Bzbase
                        + (kg1 < Bsplit ? (long)kg1 * Brs : BplOff + (long)(kg1 - Bsplit) * Brs)
                        + col0 + np * 8;
                const short8v tv = *(const short8v*)(Bv + roff);
                #pragma unroll
                for (int jj = 0; jj < 8; ++jj) u1[jj] = (ushort)tv[jj];
            }
            const int blk = (kp >> 2) ^ (np & 7);
            #pragma unroll
            for (int jj = 0; jj < 8; ++jj) {
                const int n = np * 8 + jj;
                ushort2 pr; pr.x = u0[jj]; pr.y = u1[jj];
                *(ushort2*)&Bs[n][blk * 8 + ((2 * kp) & 7)] = pr;
            }
        }
        __syncthreads();
        // exact skip: second 32-k slice is all >= Kreal (staged zeros) in K2/K4 tail
        const int nks = (k0 + 32 < Kreal) ? 2 : 1;
        for (int ks = 0; ks < nks; ++ks) {
            const int koff = ks * 32 + fg * 8;
            short8v a[4], b[4];
            #pragma unroll
            for (int mi = 0; mi < 4; ++mi) a[mi] = *(const short8v*)&As[wr + mi * 16 + fr][koff];
            #pragma unroll
            for (int ni = 0; ni < 4; ++ni) {
                const int n = wc + ni * 16 + fr;
                const int blk = (koff >> 3) ^ ((n >> 3) & 7);
                b[ni] = *(const short8v*)&Bs[n][blk * 8];
            }
            #pragma unroll
            for (int mi = 0; mi < 4; ++mi)
                #pragma unroll
                for (int ni = 0; ni < 4; ++ni)
                    acc[mi][ni] = __builtin_amdgcn_mfma_f32_16x16x32_bf16(
                            a[mi], b[ni], acc[mi][ni], 0, 0, 0);
        }
        __syncthreads();
    }
    #pragma unroll
    for (int mi = 0; mi < 4; ++mi) {
        #pragma unroll
        for (int rq = 0; rq < 4; ++rq) {
            const int rho = mt * 128 + wr + mi * 16 + fg * 4 + rq;
            if (rho >= Climit) continue;
            const long rbase = Czbase
                    + (rho < Csplit ? (long)rho * Crs : CplOff + (long)(rho - Csplit) * Crs);
            #pragma unroll
            for (int ni = 0; ni < 4; ++ni) {
                const long caddr = rbase + col0 + wc + ni * 16 + fr;
                float v = acc[mi][ni][rq];
                if (EPI == 1) v += b2f(Cv[caddr]);
                Cv[caddr] = f2b(v);
            }
        }
    }
}

// ======== fused block-diagonal complex 2-layer MLP: both layers in one kernel ========
__global__ __launch_bounds__(256) void bmm_fused(
        ushort* __restrict__ F2,
        const ushort* __restrict__ Wc1, const ushort* __restrict__ Wc2,
        const float* __restrict__ bias1, const float* __restrict__ bias2,
        const float* __restrict__ sRp, const float* __restrict__ bRp,
        const float* __restrict__ sIp, const float* __restrict__ bIp)
{
    const int MT = 40;
    const int wg = blockIdx.x;
    const int mt = wg % MT;
    const int n  = (wg / MT) & 7;
    const int bl = wg / (MT * 8);
    const long FB = (long)bl * PERB2;
    const int r0 = mt * 128;
    __shared__ ushort As[128][64];    // phase A: F2 rows; phase B: Wc2 k 0..63
    __shared__ ushort Ws[128][64];    // phase A: Wc1 slice; phase B: Wc2 k 64..127
    __shared__ ushort Ms[128][136];   // o1 tile bf16, padded rows (272B)
    const int t = threadIdx.x;
    const int lane = t & 63, wid = t >> 6;
    const int wr = (wid >> 1) * 64, wc = (wid & 1) * 64;
    const int fr = lane & 15, fg = lane >> 4;
    const int lr = lane >> 3;
    const int swz = ((lane & 7) ^ lr) * 8;

    f32x4 acc[4][4];
    #pragma unroll
    for (int i = 0; i < 4; ++i)
        #pragma unroll
        for (int j = 0; j < 4; ++j) acc[i][j] = (f32x4){0.f, 0.f, 0.f, 0.f};

    // ---- phase A (identical to verified gemm_bmm<0> loop) ----
    for (int step = 0; step < 2; ++step) {
        #pragma unroll
        for (int i = 0; i < 4; ++i) {
            const int seg = wid * 4 + i;
            const int row = seg * 8 + lr;
            const long r = r0 + row;
            gload16(F2 + FB + (step ? PL : 0) + r * 512 + n * 64 + swz, &As[seg * 8][0]);
            gload16(Wc1 + ((long)n << 14) + (long)row * 128 + step * 64 + swz, &Ws[seg * 8][0]);
        }
        __syncthreads();
        #pragma unroll
        for (int ks = 0; ks < 2; ++ks) {
            const int bc = (ks * 64 + fg * 16) ^ ((fr & 7) << 4);
            short8v a[4], b[4];
            #pragma unroll
            for (int mi = 0; mi < 4; ++mi) {
                const int row = wr + mi * 16 + fr;
                a[mi] = *(const short8v*)((const char*)&As[0][0] + row * 128 + bc);
            }
            #pragma unroll
            for (int ni = 0; ni < 4; ++ni) {
                const int row = wc + ni * 16 + fr;
                b[ni] = *(const short8v*)((const char*)&Ws[0][0] + row * 128 + bc);
            }
            #pragma unroll
            for (int mi = 0; mi < 4; ++mi)
                #pragma unroll
                for (int ni = 0; ni < 4; ++ni)
                    acc[mi][ni] = __builtin_amdgcn_mfma_f32_16x16x32_bf16(
                            a[mi], b[ni], acc[mi][ni], 0, 0, 0);
        }
        __syncthreads();
    }
    // ---- transition: Ms = star_relu(o1); stage full Wc2 into As (k<64) + Ws (k>=64) ----
    #pragma unroll
    for (int r4 = 0; r4 < 4; ++r4) {
        const int g = r4 * 4 + wid;
        const int row = g * 8 + (lane >> 3);
        const int src = ((lane & 7) ^ (row & 7)) * 8;
        gload16(Wc2 + ((long)n << 14) + (long)row * 128 + src,
                (ushort*)((char*)&As[0][0] + g * 1024));
        gload16(Wc2 + ((long)n << 14) + (long)row * 128 + 64 + src,
                (ushort*)((char*)&Ws[0][0] + g * 1024));
    }
    {
        const float sR = sRp[0], bR = bRp[0], sI = sIp[0], bI = bIp[0];
        #pragma unroll
        for (int mi = 0; mi < 4; ++mi)
            #pragma unroll
            for (int rq = 0; rq < 4; ++rq) {
                const int row = wr + mi * 16 + fg * 4 + rq;
                #pragma unroll
                for (int ni = 0; ni < 4; ++ni) {
                    const int j = wc + ni * 16 + fr;
                    const float u = acc[mi][ni][rq] + bias1[(j < 64 ? 0 : 512) + n * 64 + (j & 63)];
                    const float s  = (j < 64) ? sR : sI;
                    const float bb = (j < 64) ? bR : bI;
                    const float rl = fmaxf(u, 0.f);
                    Ms[row][j] = f2b(s * rl * rl + bb);
                }
            }
    }
    __syncthreads();        // Ms visible + Wc2 gloads drained (phase B reads them)
    // ---- phase B: barrier-free (Ms + As/Ws read-only) ----
    #pragma unroll
    for (int i = 0; i < 4; ++i)
        #pragma unroll
        for (int j = 0; j < 4; ++j) acc[i][j] = (f32x4){0.f, 0.f, 0.f, 0.f};
    #pragma unroll
    for (int step = 0; step < 2; ++step) {
        const char* basep = step ? (const char*)&Ws[0][0] : (const char*)&As[0][0];
        #pragma unroll
        for (int ks = 0; ks < 2; ++ks) {
            const int bc = (ks * 64 + fg * 16) ^ ((fr & 7) << 4);
            short8v a[4], b[4];
            #pragma unroll
            for (int mi = 0; mi < 4; ++mi) {
                const int row = wr + mi * 16 + fr;
                a[mi] = *(const short8v*)((const char*)&Ms[0][0]
                        + row * 272 + step * 128 + ks * 64 + fg * 16);
            }
            #pragma unroll
            for (int ni = 0; ni < 4; ++ni) {
                const int row = wc + ni * 16 + fr;
                b[ni] = *(const short8v*)(basep + row * 128 + bc);
            }
            #pragma unroll
            for (int mi = 0; mi < 4; ++mi)
                #pragma unroll
                for (int ni = 0; ni < 4; ++ni)
                    acc[mi][ni] = __builtin_amdgcn_mfma_f32_16x16x32_bf16(
                            a[mi], b[ni], acc[mi][ni], 0, 0, 0);
        }
    }
    // ---- epilogue: F2 = (o2 + b2) * F2 ----
    #pragma unroll
    for (int mi = 0; mi < 4; ++mi) {
        #pragma unroll
        for (int rq = 0; rq < 4; ++rq) {
            const int r = r0 + wr + mi * 16 + fg * 4 + rq;
            if (r >= 5100) continue;
            #pragma unroll
            for (int ni = 0; ni < 4; ++ni) {
                const int j = wc + ni * 16 + fr;
                const float u = acc[mi][ni][rq] + bias2[(j < 64 ? 0 : 512) + n * 64 + (j & 63)];
                const long ma = FB + (j < 64 ? 0 : PL) + (long)r * 512 + n * 64 + (j & 63);
                F2[ma] = f2b(u * b2f(F2[ma]));
            }
        }
    }
}

// ================= launcher =================
extern "C" void kernel_launch(void* const* d_in, const int* in_sizes, int n_in,
                              void* d_out, int out_size, void* d_ws, size_t ws_size,
                              hipStream_t stream) {
    (void)in_sizes; (void)n_in; (void)out_size;
    const float* x        = (const float*)d_in[0];
    const float* ln1_g    = (const float*)d_in[1];
    const float* ln1_b    = (const float*)d_in[2];
    const float* pw1_w    = (const float*)d_in[3];
    const float* act1_s   = (const float*)d_in[4];
    const float* act1_b   = (const float*)d_in[5];
    const float* w1       = (const float*)d_in[6];
    const float* w11      = (const float*)d_in[7];
    const float* b1       = (const float*)d_in[8];
    const float* w2       = (const float*)d_in[9];
    const float* w22      = (const float*)d_in[10];
    const float* b2       = (const float*)d_in[11];
    const float* actr_s   = (const float*)d_in[12];
    const float* actr_b   = (const float*)d_in[13];
    const float* acti_s   = (const float*)d_in[14];
    const float* acti_b   = (const float*)d_in[15];
    const float* pw2_w    = (const float*)d_in[16];
    const float* ln2_g    = (const float*)d_in[17];
    const float* ln2_b    = (const float*)d_in[18];
    const float* fc1_w    = (const float*)d_in[19];
    const float* mlp_s    = (const float*)d_in[20];
    const float* mlp_b    = (const float*)d_in[21];
    const float* fc2_w    = (const float*)d_in[22];
    float* out = (float*)d_out;
    float* ws  = (float*)d_ws;

    const size_t HBUF_F = 40960000ull;          // h16 region (bf16 uses half)
    const size_t MATS_F = 610000ull;
    const size_t ws_floats = ws_size / 4;
    int CB = 4;                                 // L3 sweet spot: all freq buffers resident
    while (CB > 1 && HBUF_F + (size_t)CB * (size_t)PERB2 + MATS_F > ws_floats) CB >>= 1;

    float* hbuf = ws;
    ushort* h16 = (ushort*)hbuf;                 // [80000][512] bf16
    ushort* tA16 = (ushort*)(ws + HBUF_F);       // CB*PERB2 ushorts
    ushort* tB16 = tA16 + (size_t)CB * PERB2;
    ushort* mats = tB16 + (size_t)CB * PERB2;
    ushort* A1m  = mats;
    ushort* A2m  = A1m + 16384;
    ushort* A4m  = A2m + 65536;
    ushort* A5m  = A4m + 65536;
    ushort* Wc1  = A5m + 16384;
    ushort* Wc2  = Wc1 + 131072;
    ushort* wt1  = Wc2 + 131072;
    ushort* wt2  = wt1 + 131072;
    ushort* wtf1 = wt2 + 131072;
    ushort* wtf2 = wtf1 + 262144;

    ushort* y16 = (ushort*)out;                          // LN1 out (scratch until pw2)
    ushort* y2  = (ushort*)hbuf;                         // LN2 out (h16 dead after pw2)

    build_all<<<4736, 256, 0, stream>>>(w1, w11, w2, w22, pw1_w, pw2_w, fc1_w, fc2_w,
            A1m, A2m, A4m, A5m, Wc1, Wc2, wt1, wt2, wtf1, wtf2);

    // ---- token mixer ----
    ln_fast<<<NPOS / 4, 256, 0, stream>>>(x, ln1_g, ln1_b, y16);
    gemm_mfma<3><<<(NPOS / 128) * (MED / 128), 256, 0, stream>>>(
            y16, wt1, nullptr, h16, nullptr, act1_s, act1_b, NPOS, MED, DIM);

    for (int b0 = 0; b0 < 8; b0 += CB) {
        ushort* hchunk = h16 + (size_t)b0 * (SZ * SZ * MED);
        // K1: rfft along W -> tA
        gemm_dft<0><<<CB * 100 * 4, 256, 0, stream>>>(
                A1m, 128, hchunk, 1, 51200, 0, 512, 100, 0, 100, 2,
                tA16, 100, PERB2, HROW, 512, 51, PL, 102, 4, 1);
        // K2: forward DFT along H: tA -> tB
        gemm_dft<0><<<CB * 408, 256, 0, stream>>>(
                A2m, 256, tA16, 1, PERB2, 0, HROW, 100, PL, 200, 4,
                tB16, 1, PERB2, 0, HROW, 100, PL, 200, 204, 2);
        // fused bmm: both complex-MLP layers, F2 updated in place (no G1 round-trip)
        bmm_fused<<<CB * 320, 256, 0, stream>>>(
                tB16, Wc1, Wc2, b1, b2, actr_s, actr_b, acti_s, acti_b);
        // K4: inverse DFT along H: tB -> tA
        gemm_dft<0><<<CB * 408, 256, 0, stream>>>(
                A4m, 256, tB16, 1, PERB2, 0, HROW, 100, PL, 200, 4,
                tA16, 1, PERB2, 0, HROW, 100, PL, 200, 204, 2);
        // K5: irfft along W + skip accumulate into bf16 h
        gemm_dft<1><<<CB * 100 * 4, 256, 0, stream>>>(
                A5m, 128, tA16, 100, PERB2, HROW, 512, 51, PL, 102, 2,
                hchunk, 1, 51200, 0, 512, 100, 0, 100, 4, 1);
    }

    gemm_mfma<2><<<(NPOS / 128) * (DIM / 128), 256, 0, stream>>>(
            h16, wt2, out, nullptr, x, nullptr, nullptr, NPOS, DIM, MED);

    // ---- MLP branch: LN2 + fused MLP v7 (benched best) ----
    ln_fast<<<NPOS / 4, 256, 0, stream>>>(out, ln2_g, ln2_b, y2);
    mlp_fused<<<NPOS / 128, 512, 0, stream>>>(y2, wtf1, wtf2, out, mlp_s, mlp_b);
}